// Round 2
// baseline (2584.517 us; speedup 1.0000x reference)
//
#include <hip/hip_runtime.h>
#include <cstddef>
#include <cstdint>

// ---------------------------------------------------------------------------
// Problem constants (from reference): N=50000 nodes, E=1,650,000 edges
// (1.6M random + 50k self loops). Stage dims (in,out): (512,384),(384,256),
// (256,128), final FC 128->128. All fp32.
//
// Restructuring: (A h) W^T == A (h W^T) and row-scaling commutes with W^T,
// so we GEMM first, then aggregate on the smaller output dim.
// ---------------------------------------------------------------------------

// ---------------- degree / CSR build ----------------

__global__ __launch_bounds__(256) void deg_kernel(
    const int* __restrict__ src, const int* __restrict__ dst,
    int* __restrict__ in_deg, int* __restrict__ out_deg, int E) {
  int e = blockIdx.x * 256 + threadIdx.x;
  if (e < E) {
    atomicAdd(&in_deg[dst[e]], 1);
    atomicAdd(&out_deg[src[e]], 1);
  }
}

// exclusive scan of deg[0..n) -> row_ptr[0..n], row_ptr[n] = total
__global__ __launch_bounds__(1024) void scan_kernel(
    const int* __restrict__ deg, int* __restrict__ row_ptr, int n) {
  __shared__ int buf[1024];
  __shared__ int carry_s;
  if (threadIdx.x == 0) carry_s = 0;
  __syncthreads();
  for (int base = 0; base < n; base += 1024) {
    int i = base + (int)threadIdx.x;
    int v = (i < n) ? deg[i] : 0;
    buf[threadIdx.x] = v;
    __syncthreads();
    #pragma unroll
    for (int off = 1; off < 1024; off <<= 1) {
      int t = 0;
      if ((int)threadIdx.x >= off) t = buf[threadIdx.x - off];
      __syncthreads();
      buf[threadIdx.x] += t;
      __syncthreads();
    }
    int incl  = buf[threadIdx.x];
    int carry = carry_s;
    int total = buf[1023];
    __syncthreads();  // all reads of carry_s/buf done before updates
    if (i < n) row_ptr[i] = carry + incl - v;
    if (threadIdx.x == 0) carry_s = carry + total;
    __syncthreads();
  }
  if (threadIdx.x == 0) row_ptr[n] = carry_s;
}

__global__ __launch_bounds__(256) void scatter_kernel(
    const int* __restrict__ src, const int* __restrict__ dst,
    const int* __restrict__ row_ptr, int* __restrict__ cnt,
    int* __restrict__ csr, int E) {
  int e = blockIdx.x * 256 + threadIdx.x;
  if (e < E) {
    int d = dst[e];
    int pos = row_ptr[d] + atomicAdd(&cnt[d], 1);
    csr[pos] = src[e];
  }
}

__global__ __launch_bounds__(256) void scaler_kernel(
    const int* __restrict__ in_deg, const int* __restrict__ out_deg,
    float* __restrict__ inv_src, float* __restrict__ inv_dst,
    float* __restrict__ inv_den, int n) {
  int i = blockIdx.x * 256 + threadIdx.x;
  if (i < n) {
    float od = (float)out_deg[i];
    float id = (float)in_deg[i];
    inv_src[i] = rsqrtf(od > 0.f ? od : 1.0f);
    inv_dst[i] = rsqrtf(id > 0.f ? id : 1.0f);
    inv_den[i] = 1.0f / (id + 1.0f);
  }
}

// ---------------- fp32 tiled GEMM: C[M x Nc] = A[M x K] @ W^T ----------------
// W is row-major [Nc x K]. Optional epilogue: per-row scale (inv_src fold for
// GraphConv) and bias (final FC). Nc % 128 == 0, K % 8 == 0 always hold here.

__global__ __launch_bounds__(256) void sgemm128(
    const float* __restrict__ A, const float* __restrict__ W,
    float* __restrict__ C, int M, int K, int Nc,
    const float* __restrict__ row_scale, const float* __restrict__ bias) {
  __shared__ float As[8][128];
  __shared__ float Bs[8][128];
  const int tid = threadIdx.x;
  const int bm = blockIdx.x * 128;
  const int bn = blockIdx.y * 128;
  const int lr = tid >> 1;          // 0..127: A row / W row (=col j of C)
  const int lk = (tid & 1) * 4;     // 0 or 4 within the 8-wide K slice
  const int ty = tid >> 4;          // 0..15
  const int tx = tid & 15;          // 0..15

  float acc[8][8];
  #pragma unroll
  for (int i = 0; i < 8; ++i)
    #pragma unroll
    for (int j = 0; j < 8; ++j) acc[i][j] = 0.f;

  const bool a_ok = (bm + lr) < M;
  const float* Aptr = A + (size_t)(bm + lr) * K + lk;
  const float* Wptr = W + (size_t)(bn + lr) * K + lk;

  for (int k0 = 0; k0 < K; k0 += 8) {
    float4 a4 = a_ok ? *(const float4*)(Aptr + k0) : make_float4(0.f, 0.f, 0.f, 0.f);
    float4 b4 = *(const float4*)(Wptr + k0);
    __syncthreads();
    As[lk + 0][lr] = a4.x; As[lk + 1][lr] = a4.y; As[lk + 2][lr] = a4.z; As[lk + 3][lr] = a4.w;
    Bs[lk + 0][lr] = b4.x; Bs[lk + 1][lr] = b4.y; Bs[lk + 2][lr] = b4.z; Bs[lk + 3][lr] = b4.w;
    __syncthreads();
    #pragma unroll
    for (int kk = 0; kk < 8; ++kk) {
      float ar[8], br[8];
      *(float4*)&ar[0] = *(const float4*)&As[kk][ty * 8 + 0];
      *(float4*)&ar[4] = *(const float4*)&As[kk][ty * 8 + 4];
      *(float4*)&br[0] = *(const float4*)&Bs[kk][tx * 8 + 0];
      *(float4*)&br[4] = *(const float4*)&Bs[kk][tx * 8 + 4];
      #pragma unroll
      for (int i = 0; i < 8; ++i)
        #pragma unroll
        for (int j = 0; j < 8; ++j) acc[i][j] += ar[i] * br[j];
    }
  }

  float bv[8];
  #pragma unroll
  for (int j = 0; j < 8; ++j) bv[j] = bias ? bias[bn + tx * 8 + j] : 0.f;

  #pragma unroll
  for (int i = 0; i < 8; ++i) {
    int m = bm + ty * 8 + i;
    if (m < M) {
      float rs = row_scale ? row_scale[m] : 1.0f;
      float* crow = C + (size_t)m * Nc + bn + tx * 8;
      #pragma unroll
      for (int j = 0; j < 8; j += 4) {
        float4 v;
        v.x = acc[i][j + 0] * rs + bv[j + 0];
        v.y = acc[i][j + 1] * rs + bv[j + 1];
        v.z = acc[i][j + 2] * rs + bv[j + 2];
        v.w = acc[i][j + 3] * rs + bv[j + 3];
        *(float4*)(crow + j) = v;
      }
    }
  }
}

// ---------------- CSR aggregation (wave/group per node) ----------------
// out[n] = relu( (sum_{e: dst=n} Z[csr[e]]  (+ Z[n] if SELF)) * out_scale[n] + bias )
// SELF=true  -> SAGE 'gcn' (out_scale = 1/(in_deg+1))
// SELF=false -> GraphConv (Z already row-scaled by inv_src; out_scale = inv_dst)

template <int D, int GROUP, bool SELF>
__global__ __launch_bounds__(256) void agg_kernel(
    const float* __restrict__ Z, const int* __restrict__ row_ptr,
    const int* __restrict__ csr, const float* __restrict__ out_scale,
    const float* __restrict__ bias, float* __restrict__ out, int n) {
  constexpr int DV  = D / 4;                       // float4 per row
  constexpr int NV  = (DV + GROUP - 1) / GROUP;    // float4 per lane
  constexpr int GPB = 256 / GROUP;                 // nodes per block
  const int gid  = threadIdx.x / GROUP;
  const int lane = threadIdx.x % GROUP;
  const int node = blockIdx.x * GPB + gid;
  if (node >= n) return;

  const int rs = row_ptr[node];
  const int re = row_ptr[node + 1];

  float4 acc[NV];
  #pragma unroll
  for (int v = 0; v < NV; ++v) acc[v] = make_float4(0.f, 0.f, 0.f, 0.f);

  for (int e = rs; e < re; e += GROUP) {
    int m = re - e; if (m > GROUP) m = GROUP;
    int eid = 0;
    if (lane < m) eid = csr[e + lane];
    for (int j = 0; j < m; ++j) {
      int s = __shfl(eid, j, GROUP);
      const float4* zr = (const float4*)(Z + (size_t)s * D);
      #pragma unroll
      for (int v = 0; v < NV; ++v) {
        int idx = lane + v * GROUP;
        if ((DV % GROUP == 0) || idx < DV) {
          float4 t = zr[idx];
          acc[v].x += t.x; acc[v].y += t.y; acc[v].z += t.z; acc[v].w += t.w;
        }
      }
    }
  }

  const float osc = out_scale[node];
  const float4* zs = (const float4*)(Z + (size_t)node * D);
  const float4* b4 = (const float4*)bias;
  float4* o4 = (float4*)(out + (size_t)node * D);
  #pragma unroll
  for (int v = 0; v < NV; ++v) {
    int idx = lane + v * GROUP;
    if ((DV % GROUP == 0) || idx < DV) {
      float4 a = acc[v];
      if (SELF) {
        float4 t = zs[idx];
        a.x += t.x; a.y += t.y; a.z += t.z; a.w += t.w;
      }
      float4 bb = b4[idx];
      float4 r;
      r.x = fmaxf(a.x * osc + bb.x, 0.f);
      r.y = fmaxf(a.y * osc + bb.y, 0.f);
      r.z = fmaxf(a.z * osc + bb.z, 0.f);
      r.w = fmaxf(a.w * osc + bb.w, 0.f);
      o4[idx] = r;
    }
  }
}

// ---------------- host-side orchestration ----------------

static void launch_gemm(const float* A, const float* W, float* C, int M, int K,
                        int Nc, const float* row_scale, const float* bias,
                        hipStream_t st) {
  dim3 g((M + 127) / 128, Nc / 128);
  sgemm128<<<g, 256, 0, st>>>(A, W, C, M, K, Nc, row_scale, bias);
}

template <bool SELF>
static void launch_agg(int D, const float* Z, const int* rp, const int* csr,
                       const float* osc, const float* bias, float* out, int n,
                       hipStream_t st) {
  if (D == 384) {
    agg_kernel<384, 64, SELF><<<(n + 3) / 4, 256, 0, st>>>(Z, rp, csr, osc, bias, out, n);
  } else if (D == 256) {
    agg_kernel<256, 64, SELF><<<(n + 3) / 4, 256, 0, st>>>(Z, rp, csr, osc, bias, out, n);
  } else {
    agg_kernel<128, 32, SELF><<<(n + 7) / 8, 256, 0, st>>>(Z, rp, csr, osc, bias, out, n);
  }
}

extern "C" void kernel_launch(void* const* d_in, const int* in_sizes, int n_in,
                              void* d_out, int out_size, void* d_ws, size_t ws_size,
                              hipStream_t stream) {
  const float* features = (const float*)d_in[0];
  const int*   src      = (const int*)d_in[1];
  const int*   dst      = (const int*)d_in[2];
  const float* sw[3] = {(const float*)d_in[3],  (const float*)d_in[7],  (const float*)d_in[11]};
  const float* sb[3] = {(const float*)d_in[4],  (const float*)d_in[8],  (const float*)d_in[12]};
  const float* gw[3] = {(const float*)d_in[5],  (const float*)d_in[9],  (const float*)d_in[13]};
  const float* gb[3] = {(const float*)d_in[6],  (const float*)d_in[10], (const float*)d_in[14]};
  const float* fc_w  = (const float*)d_in[15];
  const float* fc_b  = (const float*)d_in[16];

  const int N = in_sizes[0] / 512;
  const int E = in_sizes[1];

  // workspace layout (all 4B types; float4 buffers at 16B-aligned offsets)
  // NOTE: no trailing backslashes in these comments (line-continuation trap!)
  char* ws = (char*)d_ws;
  float* bufA    = (float*)ws;                         // N*384 floats (activations)
  float* bufB    = bufA + (size_t)N * 384;             // N*384 floats (Z = h@W^T)
  int*   csr     = (int*)(bufB + (size_t)N * 384);     // E ints
  int*   rp      = csr + E;                            // N+1 ints
  int*   in_dg   = rp + (N + 1);                       // N ints (zeroed)
  int*   out_dg  = in_dg + N;                          // N ints (zeroed)
  int*   cnt     = out_dg + N;                         // N ints (zeroed)
  float* inv_src = (float*)(cnt + N);                  // N floats
  float* inv_dst = inv_src + N;                        // N floats
  float* inv_den = inv_dst + N;                        // N floats

  size_t needed = (size_t)(2 * 384) * N * 4 + (size_t)E * 4 + (size_t)(N + 1) * 4 +
                  (size_t)6 * N * 4;
  if (ws_size < needed) return;  // fail loudly via wrong output rather than corrupt

  (void)hipMemsetAsync(in_dg, 0, sizeof(int) * 3 * (size_t)N, stream);

  const int eb = (E + 255) / 256;
  const int nb = (N + 255) / 256;
  deg_kernel<<<eb, 256, 0, stream>>>(src, dst, in_dg, out_dg, E);
  scan_kernel<<<1, 1024, 0, stream>>>(in_dg, rp, N);
  scatter_kernel<<<eb, 256, 0, stream>>>(src, dst, rp, cnt, csr, E);
  scaler_kernel<<<nb, 256, 0, stream>>>(in_dg, out_dg, inv_src, inv_dst, inv_den, N);

  const int din[3]  = {512, 384, 256};
  const int dout[3] = {384, 256, 128};
  const float* h = features;
  for (int s = 0; s < 3; ++s) {
    // SAGE: Z = h @ sw^T ; h' = relu((sum_in Z + Z_self) * inv_den + sb)
    launch_gemm(h, sw[s], bufB, N, din[s], dout[s], nullptr, nullptr, stream);
    launch_agg<true>(dout[s], bufB, rp, csr, inv_den, sb[s], bufA, N, stream);
    // GraphConv: Z = (h' * inv_src) @ gw^T (row-scale in epilogue);
    // h'' = relu((sum_in Z) * inv_dst + gb)
    launch_gemm(bufA, gw[s], bufB, N, dout[s], dout[s], inv_src, nullptr, stream);
    launch_agg<false>(dout[s], bufB, rp, csr, inv_dst, gb[s], bufA, N, stream);
    h = bufA;
  }
  // final FC (bias, no relu) straight into d_out
  launch_gemm(h, fc_w, (float*)d_out, N, 128, 128, nullptr, fc_b, stream);
}

// Round 3
// 1363.465 us; speedup vs baseline: 1.8956x; 1.8956x over previous
//
#include <hip/hip_runtime.h>
#include <cstddef>
#include <cstdint>

// ---------------------------------------------------------------------------
// N=50000 nodes, E=1,650,000 edges (incl. self loops). Stages (in,out):
// (512,384),(384,256),(256,128), FC 128->128.
// Pipeline (all activations/weights fp16, accumulation fp32):
//   convert -> [per stage: MFMA GEMM -> CSR agg] x6 -> MFMA FC (fp32 out)
// GEMM-first restructuring: (A h) W^T == A (h W^T); row scales commute.
// ---------------------------------------------------------------------------

typedef _Float16 h8 __attribute__((ext_vector_type(8)));
typedef _Float16 h4 __attribute__((ext_vector_type(4)));
typedef float f32x4 __attribute__((ext_vector_type(4)));

// ---------------- degree / CSR build ----------------

__global__ __launch_bounds__(256) void deg_kernel(
    const int* __restrict__ src, const int* __restrict__ dst,
    int* __restrict__ in_deg, int* __restrict__ out_deg, int E) {
  int e = blockIdx.x * 256 + threadIdx.x;
  if (e < E) {
    atomicAdd(&in_deg[dst[e]], 1);
    atomicAdd(&out_deg[src[e]], 1);
  }
}

__global__ __launch_bounds__(1024) void scan_kernel(
    const int* __restrict__ deg, int* __restrict__ row_ptr, int n) {
  __shared__ int buf[1024];
  __shared__ int carry_s;
  if (threadIdx.x == 0) carry_s = 0;
  __syncthreads();
  for (int base = 0; base < n; base += 1024) {
    int i = base + (int)threadIdx.x;
    int v = (i < n) ? deg[i] : 0;
    buf[threadIdx.x] = v;
    __syncthreads();
    #pragma unroll
    for (int off = 1; off < 1024; off <<= 1) {
      int t = 0;
      if ((int)threadIdx.x >= off) t = buf[threadIdx.x - off];
      __syncthreads();
      buf[threadIdx.x] += t;
      __syncthreads();
    }
    int incl  = buf[threadIdx.x];
    int carry = carry_s;
    int total = buf[1023];
    __syncthreads();
    if (i < n) row_ptr[i] = carry + incl - v;
    if (threadIdx.x == 0) carry_s = carry + total;
    __syncthreads();
  }
  if (threadIdx.x == 0) row_ptr[n] = carry_s;
}

__global__ __launch_bounds__(256) void scatter_kernel(
    const int* __restrict__ src, const int* __restrict__ dst,
    const int* __restrict__ row_ptr, int* __restrict__ cnt,
    int* __restrict__ csr, int E) {
  int e = blockIdx.x * 256 + threadIdx.x;
  if (e < E) {
    int d = dst[e];
    int pos = row_ptr[d] + atomicAdd(&cnt[d], 1);
    csr[pos] = src[e];
  }
}

__global__ __launch_bounds__(256) void scaler_kernel(
    const int* __restrict__ in_deg, const int* __restrict__ out_deg,
    float* __restrict__ inv_src, float* __restrict__ inv_dst,
    float* __restrict__ inv_den, int n) {
  int i = blockIdx.x * 256 + threadIdx.x;
  if (i < n) {
    float od = (float)out_deg[i];
    float id = (float)in_deg[i];
    inv_src[i] = rsqrtf(od > 0.f ? od : 1.0f);
    inv_dst[i] = rsqrtf(id > 0.f ? id : 1.0f);
    inv_den[i] = 1.0f / (id + 1.0f);
  }
}

// ---------------- fp32 -> fp16 conversion (pad region zeroed) ----------------

__global__ __launch_bounds__(256) void cvt_kernel(
    const float* __restrict__ in, _Float16* __restrict__ out,
    long n_in, long n_pad) {
  long i = ((long)blockIdx.x * 256 + (long)threadIdx.x) * 4;
  if (i >= n_pad) return;
  float4 v = (i < n_in) ? *(const float4*)(in + i) : make_float4(0.f, 0.f, 0.f, 0.f);
  h4 h = {(_Float16)v.x, (_Float16)v.y, (_Float16)v.z, (_Float16)v.w};
  *(h4*)(out + i) = h;
}

// ---------------- fp16 MFMA GEMM: C[M x Nc] = A[M x K] @ W^T ----------------
// A padded to a multiple of 128 rows (pad rows hold finite junk; their C rows
// are discarded by the m<Mstore store guard). W row-major [Nc x K]. Epilogue:
// optional per-row scale + bias. 256 thr = 4 waves (2x2), 64x64/wave,
// 16x16x32_f16 MFMA, BK=32, LDS 2x8KB.
// Fragment layouts (HW-verified, guide §3): A/B lane l: idx=l&15, k=(l>>4)*8+j;
// C/D lane l: col=l&15, row=(l>>4)*4+reg.

template <typename OutT>
__global__ __launch_bounds__(256) void hgemm(
    const _Float16* __restrict__ A, const _Float16* __restrict__ W,
    OutT* __restrict__ C, int Mstore, int K, int Nc,
    const float* __restrict__ row_scale, const float* __restrict__ bias) {
  __shared__ _Float16 As[128 * 32];
  __shared__ _Float16 Bs[128 * 32];
  const int tid = threadIdx.x;
  const int bm = blockIdx.x * 128, bn = blockIdx.y * 128;
  const int wave = tid >> 6, lane = tid & 63;
  const int wm = (wave & 1) * 64, wn = (wave >> 1) * 64;
  const int lrow = lane & 15, lq = lane >> 4;

  // staging: chunk tid covers row tid>>2, 8 halves at col (tid&3)*8;
  // second chunk is row+64 same col. Wave reads 16 rows x 64B contiguous.
  const int r0 = tid >> 2;
  const int cc = (tid & 3) * 8;
  const _Float16* Ag = A + (size_t)(bm + r0) * K + cc;
  const _Float16* Wg = W + (size_t)(bn + r0) * K + cc;
  const size_t rs64 = (size_t)64 * K;

  f32x4 acc[4][4];
  #pragma unroll
  for (int i = 0; i < 4; ++i)
    #pragma unroll
    for (int j = 0; j < 4; ++j) acc[i][j] = (f32x4){0.f, 0.f, 0.f, 0.f};

  for (int k0 = 0; k0 < K; k0 += 32) {
    uint4 a0 = *(const uint4*)(Ag + k0);
    uint4 a1 = *(const uint4*)(Ag + rs64 + k0);
    uint4 b0 = *(const uint4*)(Wg + k0);
    uint4 b1 = *(const uint4*)(Wg + rs64 + k0);
    __syncthreads();
    *(uint4*)(As + r0 * 32 + cc) = a0;
    *(uint4*)(As + (64 + r0) * 32 + cc) = a1;
    *(uint4*)(Bs + r0 * 32 + cc) = b0;
    *(uint4*)(Bs + (64 + r0) * 32 + cc) = b1;
    __syncthreads();
    h8 af[4], bf[4];
    #pragma unroll
    for (int i = 0; i < 4; ++i)
      af[i] = *(const h8*)(As + (wm + i * 16 + lrow) * 32 + lq * 8);
    #pragma unroll
    for (int j = 0; j < 4; ++j)
      bf[j] = *(const h8*)(Bs + (wn + j * 16 + lrow) * 32 + lq * 8);
    #pragma unroll
    for (int i = 0; i < 4; ++i)
      #pragma unroll
      for (int j = 0; j < 4; ++j)
        acc[i][j] = __builtin_amdgcn_mfma_f32_16x16x32_f16(af[i], bf[j], acc[i][j], 0, 0, 0);
  }

  #pragma unroll
  for (int i = 0; i < 4; ++i) {
    #pragma unroll
    for (int r = 0; r < 4; ++r) {
      const int m = bm + wm + i * 16 + lq * 4 + r;
      if (m < Mstore) {
        const float rsc = row_scale ? row_scale[m] : 1.0f;
        OutT* crow = C + (size_t)m * Nc + bn + wn + lrow;
        #pragma unroll
        for (int j = 0; j < 4; ++j) {
          float v = acc[i][j][r] * rsc;
          if (bias) v += bias[bn + wn + j * 16 + lrow];
          crow[j * 16] = (OutT)v;
        }
      }
    }
  }
}

// ---------------- CSR aggregation, fp16 gather / fp32 accumulate ----------------
// out[n] = relu(((sum_{e:dst=n} Z[csr[e]]) (+ Z[n] if SELF)) * out_scale[n] + bias)
// 16 lanes per node; 16B gathers; all lanes active for D in {384,256,128}.

template <int D, bool SELF>
__global__ __launch_bounds__(256) void agg_h(
    const _Float16* __restrict__ Z, const int* __restrict__ row_ptr,
    const int* __restrict__ csr, const float* __restrict__ out_scale,
    const float* __restrict__ bias, _Float16* __restrict__ out, int n) {
  constexpr int CH = D / 8;       // 16B chunks per row (48/32/16)
  constexpr int GROUP = 16;
  constexpr int NV = CH / GROUP;  // 3/2/1 chunks per lane
  const int gid = threadIdx.x >> 4;
  const int lane = threadIdx.x & 15;
  const int node = blockIdx.x * 16 + gid;
  if (node >= n) return;

  const int rs = row_ptr[node], re = row_ptr[node + 1];

  float acc[NV][8];
  #pragma unroll
  for (int v = 0; v < NV; ++v)
    #pragma unroll
    for (int q = 0; q < 8; ++q) acc[v][q] = 0.f;

  for (int e = rs; e < re; e += GROUP) {
    int m = re - e; if (m > GROUP) m = GROUP;
    int eid = (lane < m) ? csr[e + lane] : 0;
    for (int j = 0; j < m; ++j) {
      int s = __shfl(eid, j, GROUP);
      const h8* zr = (const h8*)(Z + (size_t)s * D);
      #pragma unroll
      for (int v = 0; v < NV; ++v) {
        h8 t = zr[lane + v * GROUP];
        #pragma unroll
        for (int q = 0; q < 8; ++q) acc[v][q] += (float)t[q];
      }
    }
  }

  const float osc = out_scale[node];
  const h8* zs = (const h8*)(Z + (size_t)node * D);
  _Float16* orow = out + (size_t)node * D;
  #pragma unroll
  for (int v = 0; v < NV; ++v) {
    const int idx = lane + v * GROUP;
    if (SELF) {
      h8 t = zs[idx];
      #pragma unroll
      for (int q = 0; q < 8; ++q) acc[v][q] += (float)t[q];
    }
    h8 r;
    #pragma unroll
    for (int q = 0; q < 8; ++q) {
      float x = acc[v][q] * osc + bias[idx * 8 + q];
      r[q] = (_Float16)fmaxf(x, 0.f);
    }
    *(h8*)(orow + idx * 8) = r;
  }
}

// ---------------- host-side orchestration ----------------

static void launch_cvt(const float* in, _Float16* out, long n_in, long n_pad,
                       hipStream_t st) {
  long thr = n_pad / 4;
  cvt_kernel<<<(int)((thr + 255) / 256), 256, 0, st>>>(in, out, n_in, n_pad);
}

extern "C" void kernel_launch(void* const* d_in, const int* in_sizes, int n_in,
                              void* d_out, int out_size, void* d_ws, size_t ws_size,
                              hipStream_t stream) {
  const float* features = (const float*)d_in[0];
  const int*   src      = (const int*)d_in[1];
  const int*   dst      = (const int*)d_in[2];
  const float* wsrc[7] = {(const float*)d_in[3],  (const float*)d_in[5],
                          (const float*)d_in[7],  (const float*)d_in[9],
                          (const float*)d_in[11], (const float*)d_in[13],
                          (const float*)d_in[15]};  // sw0,gw0,sw1,gw1,sw2,gw2,fc
  const float* sb[3] = {(const float*)d_in[4],  (const float*)d_in[8],  (const float*)d_in[12]};
  const float* gb[3] = {(const float*)d_in[6],  (const float*)d_in[10], (const float*)d_in[14]};
  const float* fc_b  = (const float*)d_in[16];

  const int N = in_sizes[0] / 512;
  const int E = in_sizes[1];
  const int MB = (N + 127) / 128;
  const int Mpad = MB * 128;

  const int wcnt[7] = {384 * 512, 384 * 384, 256 * 384, 256 * 256,
                       128 * 256, 128 * 128, 128 * 128};

  // workspace layout (fp16 buffers first, 16B-aligned throughout)
  char* ws = (char*)d_ws;
  _Float16* featH = (_Float16*)ws;                       // Mpad*512
  _Float16* hA    = featH + (size_t)Mpad * 512;          // Mpad*384 (activations)
  _Float16* hB    = hA + (size_t)Mpad * 384;             // Mpad*384 (Z)
  _Float16* wH[7];
  {
    _Float16* p = hB + (size_t)Mpad * 384;
    for (int i = 0; i < 7; ++i) { wH[i] = p; p += wcnt[i]; }
  }
  int* csr     = (int*)(wH[6] + wcnt[6]);                // E ints
  int* rp      = csr + E;                                // N+1
  int* in_dg   = rp + (N + 1);                           // N (zeroed)
  int* out_dg  = in_dg + N;                              // N (zeroed)
  int* cnt     = out_dg + N;                             // N (zeroed)
  float* inv_src = (float*)(cnt + N);                    // N
  float* inv_dst = inv_src + N;                          // N
  float* inv_den = inv_dst + N;                          // N

  size_t totw = 0; for (int i = 0; i < 7; ++i) totw += wcnt[i];
  size_t needed = ((size_t)Mpad * (512 + 384 + 384) + totw) * 2 +
                  ((size_t)E + (N + 1) + 6 * (size_t)N) * 4;
  if (ws_size < needed) return;

  (void)hipMemsetAsync(in_dg, 0, sizeof(int) * 3 * (size_t)N, stream);

  const int eb = (E + 255) / 256;
  const int nb = (N + 255) / 256;
  deg_kernel<<<eb, 256, 0, stream>>>(src, dst, in_dg, out_dg, E);
  scan_kernel<<<1, 1024, 0, stream>>>(in_dg, rp, N);
  scatter_kernel<<<eb, 256, 0, stream>>>(src, dst, rp, cnt, csr, E);
  scaler_kernel<<<nb, 256, 0, stream>>>(in_dg, out_dg, inv_src, inv_dst, inv_den, N);

  // conversions
  launch_cvt(features, featH, (long)N * 512, (long)Mpad * 512, stream);
  for (int i = 0; i < 7; ++i) launch_cvt(wsrc[i], wH[i], wcnt[i], wcnt[i], stream);

  const int dout[3] = {384, 256, 128};
  const _Float16* h = featH;
  int K = 512;
  for (int s = 0; s < 3; ++s) {
    const int D = dout[s];
    dim3 gg(MB, D / 128);
    const int ab = (N + 15) / 16;
    // SAGE: Z = h @ sw^T ; h' = relu((sum_in Z + Z_self)*inv_den + sb)
    hgemm<_Float16><<<gg, 256, 0, stream>>>(h, wH[2 * s], hB, Mpad, K, D, nullptr, nullptr);
    if (D == 384)      agg_h<384, true><<<ab, 256, 0, stream>>>(hB, rp, csr, inv_den, sb[s], hA, N);
    else if (D == 256) agg_h<256, true><<<ab, 256, 0, stream>>>(hB, rp, csr, inv_den, sb[s], hA, N);
    else               agg_h<128, true><<<ab, 256, 0, stream>>>(hB, rp, csr, inv_den, sb[s], hA, N);
    // GraphConv: Z = (h'*inv_src) @ gw^T ; h'' = relu((sum_in Z)*inv_dst + gb)
    hgemm<_Float16><<<gg, 256, 0, stream>>>(hA, wH[2 * s + 1], hB, Mpad, D, D, inv_src, nullptr);
    if (D == 384)      agg_h<384, false><<<ab, 256, 0, stream>>>(hB, rp, csr, inv_dst, gb[s], hA, N);
    else if (D == 256) agg_h<256, false><<<ab, 256, 0, stream>>>(hB, rp, csr, inv_dst, gb[s], hA, N);
    else               agg_h<128, false><<<ab, 256, 0, stream>>>(hB, rp, csr, inv_dst, gb[s], hA, N);
    h = hA;
    K = D;
  }
  // final FC: fp32 out + bias, no relu
  dim3 gf(MB, 1);
  hgemm<float><<<gf, 256, 0, stream>>>(h, wH[6], (float*)d_out, N, 128, 128, nullptr, fc_b);
}